// Round 10
// baseline (25.683 us; speedup 1.0000x reference)
//
#include <hip/hip_runtime.h>
#include <math.h>

// Problem constants (setup_inputs: L=8, B=2, N=2048)
constexpr int L = 8;
constexpr int B = 2;
constexpr int N = 2048;
constexpr int LB = L * B;            // 16
constexpr int KF = 32;               // padded feature dim (28 used + residual)

constexpr float D_CLAMP2 = 100.0f;   // clamp on squared distance
constexpr float FAPE_EPS = 1e-4f;
constexpr float Z_CONST  = 10.0f;
constexpr float TEPS     = 1e-8f;

constexpr int THREADS = 256;                 // 4 waves (round-8 proven config)
constexpr int IBLK    = 256;                 // i rows per block
constexpr int JCH     = 512;                 // j cols per block
constexpr int NIT     = N / IBLK;            // 8 i-tiles per (l,b)
constexpr int JSPLIT  = N / JCH;             // 4 j-chunks per (l,b)
constexpr int BLK_PER_LB  = NIT * JSPLIT;    // 32
constexpr int FAPE_BLOCKS = LB * BLK_PER_LB; // 512 (256 per b)
constexpr int BLOCKS_PER_B = FAPE_BLOCKS / B;        // 256
constexpr int TORS_PER_BLK = N / BLK_PER_LB; // 64 torsion items per block

// fixed-point scale for deterministic i64 accumulation (order-invariant).
// max sum per b ~ 0.4 * 2^55 = 2^53.7 < 2^56 (count lives in bits 56..63).
constexpr double ACC_SCALE  = 36028797018963968.0;   // 2^55
constexpr double ACC_ISCALE = 1.0 / 36028797018963968.0;
constexpr unsigned long long CNT_ONE = 1ull << 56;
constexpr unsigned long long SUM_MASK = CNT_ONE - 1ull;

typedef __attribute__((ext_vector_type(8))) short bf16x8;
typedef __attribute__((ext_vector_type(4))) float f32x4;

__device__ __forceinline__ float fast_sqrtf(float x) {
    return __builtin_amdgcn_sqrtf(x);
}
// HW packed f32->bf16 (RNE on gfx950); 1 instr per 2 values
__device__ __forceinline__ unsigned cvt_pk(float lo, float hi) {
    unsigned r;
    asm("v_cvt_pk_bf16_f32 %0, %1, %2" : "=v"(r) : "v"(lo), "v"(hi));
    return r;
}
__device__ __forceinline__ float bf2f(unsigned short h) {
    return __uint_as_float((unsigned)h << 16);
}

__device__ __forceinline__ float wave_reduce_sum(float v) {
    #pragma unroll
    for (int off = 32; off > 0; off >>= 1)
        v += __shfl_down(v, off, 64);
    return v;            // valid in lane 0
}

__device__ __forceinline__ float block_reduce_sum(float v) {
    __shared__ float s[4];
    v = wave_reduce_sum(v);
    int lane = threadIdx.x & 63;
    int w    = threadIdx.x >> 6;
    __syncthreads();
    if (lane == 0) s[w] = v;
    __syncthreads();
    return s[0] + s[1] + s[2] + s[3];   // fixed order -> deterministic
}

// LDS chunk swizzle: 16B chunk c of row r stored at position c ^ ((r>>1)&3).
// Write (64 lanes x 4 chunks) and MFMA-fragment read (16 rows x 4 k-chunks)
// both hit each bank exactly twice per wave access = structural minimum
// (verified 0 SQ_LDS_BANK_CONFLICT in rounds 7/8).
__device__ __forceinline__ void store_row(short* base, int r, const float* f) {
    #pragma unroll
    for (int c = 0; c < 4; ++c) {
        union { unsigned u[4]; bf16x8 v; } q;
        #pragma unroll
        for (int e = 0; e < 4; ++e)
            q.u[e] = cvt_pk(f[8 * c + 2 * e], f[8 * c + 2 * e + 1]);
        const int p = c ^ ((r >> 1) & 3);
        *(bf16x8*)(base + r * KF + p * 8) = q.v;
    }
}
__device__ __forceinline__ bf16x8 load_frag(const short* base, int r, int c) {
    const int p = c ^ ((r >> 1) & 3);
    return *(const bf16x8*)(base + r * KF + p * 8);
}

// ---------------------------------------------------------------------------
// Self-sufficient FAPE block (round-8 structure): 256 i x 512 j, 4 waves.
// psi (256 rows) + phi (512 rows) into LDS, torsion slice (64 items), MFMA
// pair loop, block reduce. Finish: atomicAdd(q + 1<<56) into per-b i64; the
// 256th adder's RETURN VALUE carries the complete sum -> it writes out[b].
// No fence, no partials re-read, no finalize kernel. Integer sum is
// order-invariant -> deterministic across replays.
// Factorization: ||W u_j + k||^2 + eps = psi(i) . phi(j), W=[Rp^T|-Rt^T],
// k = -W u_i.  psi: [0..5]=Q_cc, [6..20]=2Q_cd, [21..26]=2(W^T k)_c,
// [27]=|k|^2+eps, [28]=bf16 residual of [27]; phi: [u_c^2, u_c u_d, u_c, 1, 1].
// ---------------------------------------------------------------------------
__global__ __launch_bounds__(THREADS)
void fape_all_kernel(const float* __restrict__ traj_rot,    // [L,B,N,3,3]
                     const float* __restrict__ traj_trans,  // [L,B,N,3]
                     const float* __restrict__ traj_tors,   // [L,B,N,7,2]
                     const float* __restrict__ true_rot,    // [B,N,3,3]
                     const float* __restrict__ true_trans,  // [B,N,3]
                     const float* __restrict__ t_true,      // [B,N,7,2]
                     const float* __restrict__ t_alt,       // [B,N,7,2]
                     unsigned long long* __restrict__ acc64, // [2*16] padded
                     float* __restrict__ out)                // [B]
{
    __shared__ short phiL[JCH * KF];    // 32 KB
    __shared__ short psiL[IBLK * KF];   // 16 KB
    __shared__ float tors_s;

    const int bid = blockIdx.x;
    const int jh  = bid & (JSPLIT - 1);
    const int it  = (bid >> 2) & (NIT - 1);
    const int lb  = bid >> 5;            // 32 blocks per lb
    const int b   = lb & (B - 1);
    const int tid = threadIdx.x;

    const float* tp = traj_trans + (size_t)lb * N * 3;
    const float* tt = true_trans + (size_t)b  * N * 3;

    // ---- phi prep: rows tid and tid+256 ----
    #pragma unroll
    for (int half = 0; half < 2; ++half) {
        const int r = tid + half * THREADS;      // 0..511
        const int j = jh * JCH + r;
        float u[6] = { tp[3 * j], tp[3 * j + 1], tp[3 * j + 2],
                       tt[3 * j], tt[3 * j + 1], tt[3 * j + 2] };
        float phi[KF];
        #pragma unroll
        for (int c = 0; c < 6; ++c) phi[c] = u[c] * u[c];
        int idx = 6;
        #pragma unroll
        for (int c = 0; c < 6; ++c)
            #pragma unroll
            for (int d = c + 1; d < 6; ++d)
                phi[idx++] = u[c] * u[d];
        #pragma unroll
        for (int c = 0; c < 6; ++c) phi[21 + c] = u[c];
        phi[27] = 1.0f;
        phi[28] = 1.0f;
        phi[29] = phi[30] = phi[31] = 0.0f;
        store_row(phiL, r, phi);
    }

    // ---- psi prep: one i-row per thread ----
    {
        const int r = tid;
        const int i = it * IBLK + r;
        const float* Rp = traj_rot + ((size_t)lb * N + i) * 9;
        const float* Rt = true_rot + ((size_t)(b * N + i)) * 9;

        float W0[6], W1[6], W2[6];
        #pragma unroll
        for (int c = 0; c < 3; ++c) {
            W0[c] = Rp[3 * c];      W1[c] = Rp[3 * c + 1];      W2[c] = Rp[3 * c + 2];
            W0[c + 3] = -Rt[3 * c]; W1[c + 3] = -Rt[3 * c + 1]; W2[c + 3] = -Rt[3 * c + 2];
        }
        float u[6] = { tp[3 * i], tp[3 * i + 1], tp[3 * i + 2],
                       tt[3 * i], tt[3 * i + 1], tt[3 * i + 2] };

        float k0 = 0.f, k1 = 0.f, k2 = 0.f;
        #pragma unroll
        for (int c = 0; c < 6; ++c) {
            k0 = fmaf(W0[c], u[c], k0);
            k1 = fmaf(W1[c], u[c], k1);
            k2 = fmaf(W2[c], u[c], k2);
        }
        k0 = -k0; k1 = -k1; k2 = -k2;

        float psi[KF];
        #pragma unroll
        for (int c = 0; c < 6; ++c)
            psi[c] = fmaf(W0[c], W0[c], fmaf(W1[c], W1[c], W2[c] * W2[c]));
        int idx = 6;
        #pragma unroll
        for (int c = 0; c < 6; ++c)
            #pragma unroll
            for (int d = c + 1; d < 6; ++d)
                psi[idx++] = 2.0f * fmaf(W0[c], W0[d], fmaf(W1[c], W1[d], W2[c] * W2[d]));
        #pragma unroll
        for (int c = 0; c < 6; ++c)
            psi[21 + c] = 2.0f * fmaf(W0[c], k0, fmaf(W1[c], k1, W2[c] * k2));
        psi[27] = fmaf(k0, k0, fmaf(k1, k1, fmaf(k2, k2, FAPE_EPS)));
        // residual vs the SAME hw conversion the store uses -> self-consistent
        psi[28] = psi[27] - bf2f((unsigned short)(cvt_pk(psi[27], psi[27]) & 0xffffu));
        psi[29] = psi[30] = psi[31] = 0.0f;
        store_row(psiL, r, psi);
    }

    // ---- torsion: wave 0, one item per lane (64 items per block) ----
    if (tid < 64) {
        const int n  = (bid & 31) * TORS_PER_BLK + tid;
        const int g  = lb * N + n;
        const int bn = b * N + n;
        const float* p  = traj_tors + (size_t)g * 14;
        const float* tr = t_true + (size_t)bn * 14;
        const float* al = t_alt  + (size_t)bn * 14;

        float st = 0.0f, sa = 0.0f;
        #pragma unroll
        for (int k = 0; k < 7; ++k) {
            const float px = p[2 * k], py = p[2 * k + 1];
            const float nrm = fast_sqrtf(fmaf(px, px, fmaf(py, py, TEPS)));
            const float inv = __builtin_amdgcn_rcpf(nrm);
            const float pnx = px * inv, pny = py * inv;
            const float tx = tr[2 * k] - pnx, ty = tr[2 * k + 1] - pny;
            const float ax = al[2 * k] - pnx, ay = al[2 * k + 1] - pny;
            const float dt = fast_sqrtf(fmaf(tx, tx, fmaf(ty, ty, TEPS)));
            const float da = fast_sqrtf(fmaf(ax, ax, fmaf(ay, ay, TEPS)));
            st += fminf(dt, da);
            sa += fabsf(nrm - 1.0f);
        }
        float val = (st + 0.02f * sa) * (1.0f / 7.0f);
        val = wave_reduce_sum(val);
        if (tid == 0) tors_s = val;
    }

    __syncthreads();

    // ---- MFMA pair loop: 4 waves, each 128 i x 256 j ----
    const int w    = tid >> 6;
    const int lane = tid & 63;
    const int wm   = w >> 1;             // i half (128 rows)
    const int wn   = w & 1;              // j half (256 cols)
    const int r15  = lane & 15;
    const int cch  = lane >> 4;          // k-chunk 0..3

    bf16x8 a[8];                         // 8 A-frags in registers (32 VGPR)
    #pragma unroll
    for (int s = 0; s < 8; ++s)
        a[s] = load_frag(psiL, wm * 128 + s * 16 + r15, cch);

    const f32x4 z = { 0.f, 0.f, 0.f, 0.f };
    float acc0 = 0.f, acc1 = 0.f, acc2 = 0.f, acc3 = 0.f;

    #pragma unroll
    for (int jp = 0; jp < 4; ++jp) {             // 4 j-passes of 64
        const int rb = wn * 256 + jp * 64 + r15;
        #pragma unroll
        for (int q = 0; q < 4; ++q) {            // 4 B-frags per pass
            const bf16x8 bq = load_frag(phiL, rb + q * 16, cch);
            f32x4 d[8];
            #pragma unroll
            for (int s = 0; s < 8; ++s)
                d[s] = __builtin_amdgcn_mfma_f32_16x16x32_bf16(a[s], bq, z, 0, 0, 0);
            #pragma unroll
            for (int s = 0; s < 8; ++s) {
                acc0 += fast_sqrtf(__builtin_amdgcn_fmed3f(d[s][0], 0.f, D_CLAMP2));
                acc1 += fast_sqrtf(__builtin_amdgcn_fmed3f(d[s][1], 0.f, D_CLAMP2));
                acc2 += fast_sqrtf(__builtin_amdgcn_fmed3f(d[s][2], 0.f, D_CLAMP2));
                acc3 += fast_sqrtf(__builtin_amdgcn_fmed3f(d[s][3], 0.f, D_CLAMP2));
            }
        }
    }

    const float tot = block_reduce_sum((acc0 + acc1) + (acc2 + acc3));

    if (tid == 0) {
        // partial carries all scaling: /(N*N*Z*L) and /(N*L)
        const float partial = tot * (1.0f / ((float)N * (float)N * Z_CONST * (float)L))
                            + tors_s * (1.0f / ((float)N * (float)L));
        const unsigned long long q =
            (unsigned long long)(long long)((double)partial * ACC_SCALE + 0.5);
        // counter in bits 56..63; sum in bits 0..55. 256th adder sees 255.
        const unsigned long long old = atomicAdd(&acc64[b * 16], q + CNT_ONE);
        if ((old >> 56) == (unsigned long long)(BLOCKS_PER_B - 1)) {
            const unsigned long long total = (old + q + CNT_ONE) & SUM_MASK;
            out[b] = (float)((double)total * ACC_ISCALE);
        }
    }
}

extern "C" void kernel_launch(void* const* d_in, const int* in_sizes, int n_in,
                              void* d_out, int out_size, void* d_ws, size_t ws_size,
                              hipStream_t stream)
{
    const float* traj_rot   = (const float*)d_in[0];
    const float* traj_trans = (const float*)d_in[1];
    const float* traj_tors  = (const float*)d_in[2];
    const float* true_rot   = (const float*)d_in[3];
    const float* true_trans = (const float*)d_in[4];
    const float* true_ta    = (const float*)d_in[5];
    const float* true_taa   = (const float*)d_in[6];

    float* out = (float*)d_out;
    unsigned long long* acc64 = (unsigned long long*)d_ws;  // [2*16] (128B apart)

    hipMemsetAsync(acc64, 0, 32 * sizeof(unsigned long long), stream);

    fape_all_kernel<<<FAPE_BLOCKS, THREADS, 0, stream>>>(
        traj_rot, traj_trans, traj_tors, true_rot, true_trans,
        true_ta, true_taa, acc64, out);
}

// Round 11
// 20.770 us; speedup vs baseline: 1.2365x; 1.2365x over previous
//
#include <hip/hip_runtime.h>
#include <math.h>

// Problem constants (setup_inputs: L=8, B=2, N=2048)
constexpr int L = 8;
constexpr int B = 2;
constexpr int N = 2048;
constexpr int LB = L * B;            // 16
constexpr int KF = 32;               // padded feature dim (28 used + residual)

constexpr float D_CLAMP2 = 100.0f;   // clamp on squared distance
constexpr float FAPE_EPS = 1e-4f;
constexpr float Z_CONST  = 10.0f;
constexpr float TEPS     = 1e-8f;

constexpr int THREADS = 256;                 // 4 waves
constexpr int IBLK    = 128;                 // i rows per block (R8: 256)
constexpr int JCH     = 512;                 // j cols per block
constexpr int NIT     = N / IBLK;            // 16 i-tiles per (l,b)
constexpr int JSPLIT  = N / JCH;             // 4 j-chunks per (l,b)
constexpr int BLK_PER_LB  = NIT * JSPLIT;    // 64
constexpr int FAPE_BLOCKS = LB * BLK_PER_LB; // 1024 -> 4 blocks/CU (40KB LDS)
constexpr int TORS_PER_BLK = N / BLK_PER_LB; // 32 torsion items per block

typedef __attribute__((ext_vector_type(8))) short bf16x8;
typedef __attribute__((ext_vector_type(4))) float f32x4;

__device__ __forceinline__ float fast_sqrtf(float x) {
    return __builtin_amdgcn_sqrtf(x);
}
// HW packed f32->bf16 (RNE on gfx950); 1 instr per 2 values
__device__ __forceinline__ unsigned cvt_pk(float lo, float hi) {
    unsigned r;
    asm("v_cvt_pk_bf16_f32 %0, %1, %2" : "=v"(r) : "v"(lo), "v"(hi));
    return r;
}
__device__ __forceinline__ float bf2f(unsigned short h) {
    return __uint_as_float((unsigned)h << 16);
}

__device__ __forceinline__ float wave_reduce_sum(float v) {
    #pragma unroll
    for (int off = 32; off > 0; off >>= 1)
        v += __shfl_down(v, off, 64);
    return v;            // valid in lane 0
}

__device__ __forceinline__ float block_reduce_sum(float v) {
    __shared__ float s[4];
    v = wave_reduce_sum(v);
    int lane = threadIdx.x & 63;
    int w    = threadIdx.x >> 6;
    __syncthreads();
    if (lane == 0) s[w] = v;
    __syncthreads();
    return s[0] + s[1] + s[2] + s[3];   // fixed order -> deterministic
}

// LDS chunk swizzle: 16B chunk c of row r stored at position c ^ ((r>>1)&3).
// Write (64 lanes x 4 chunks) and MFMA-fragment read (16 rows x 4 k-chunks)
// both hit each bank exactly twice per wave access = structural minimum
// (verified 0 SQ_LDS_BANK_CONFLICT in rounds 7-10).
__device__ __forceinline__ void store_row(short* base, int r, const float* f) {
    #pragma unroll
    for (int c = 0; c < 4; ++c) {
        union { unsigned u[4]; bf16x8 v; } q;
        #pragma unroll
        for (int e = 0; e < 4; ++e)
            q.u[e] = cvt_pk(f[8 * c + 2 * e], f[8 * c + 2 * e + 1]);
        const int p = c ^ ((r >> 1) & 3);
        *(bf16x8*)(base + r * KF + p * 8) = q.v;
    }
}
__device__ __forceinline__ bf16x8 load_frag(const short* base, int r, int c) {
    const int p = c ^ ((r >> 1) & 3);
    return *(const bf16x8*)(base + r * KF + p * 8);
}

// ---------------------------------------------------------------------------
// Self-sufficient FAPE block (round-8 structure, higher occupancy):
// 128 i x 512 j, 4 waves, 40KB LDS -> 4 blocks/CU, 4 waves/SIMD.
// psi (128 rows) + phi (512 rows) into LDS, torsion slice (32 items on
// wave 3), MFMA pair loop, block reduce, one float partial per block.
// Factorization: ||W u_j + k||^2 + eps = psi(i) . phi(j), W=[Rp^T|-Rt^T],
// k = -W u_i.  psi: [0..5]=Q_cc, [6..20]=2Q_cd, [21..26]=2(W^T k)_c,
// [27]=|k|^2+eps, [28]=bf16 residual of [27]; phi: [u_c^2, u_c u_d, u_c, 1, 1].
// ---------------------------------------------------------------------------
__global__ __launch_bounds__(THREADS)
void fape_all_kernel(const float* __restrict__ traj_rot,    // [L,B,N,3,3]
                     const float* __restrict__ traj_trans,  // [L,B,N,3]
                     const float* __restrict__ traj_tors,   // [L,B,N,7,2]
                     const float* __restrict__ true_rot,    // [B,N,3,3]
                     const float* __restrict__ true_trans,  // [B,N,3]
                     const float* __restrict__ t_true,      // [B,N,7,2]
                     const float* __restrict__ t_alt,       // [B,N,7,2]
                     float* __restrict__ partials)          // [FAPE_BLOCKS]
{
    __shared__ short phiL[JCH * KF];    // 32 KB
    __shared__ short psiL[IBLK * KF];   // 8 KB
    __shared__ float tors_s;

    const int bid = blockIdx.x;
    const int jh  = bid & (JSPLIT - 1);
    const int it  = (bid >> 2) & (NIT - 1);
    const int lb  = bid >> 6;            // 64 blocks per lb
    const int b   = lb & (B - 1);
    const int tid = threadIdx.x;

    const float* tp = traj_trans + (size_t)lb * N * 3;
    const float* tt = true_trans + (size_t)b  * N * 3;

    // ---- phi prep: rows tid and tid+256 ----
    #pragma unroll
    for (int half = 0; half < 2; ++half) {
        const int r = tid + half * THREADS;      // 0..511
        const int j = jh * JCH + r;
        float u[6] = { tp[3 * j], tp[3 * j + 1], tp[3 * j + 2],
                       tt[3 * j], tt[3 * j + 1], tt[3 * j + 2] };
        float phi[KF];
        #pragma unroll
        for (int c = 0; c < 6; ++c) phi[c] = u[c] * u[c];
        int idx = 6;
        #pragma unroll
        for (int c = 0; c < 6; ++c)
            #pragma unroll
            for (int d = c + 1; d < 6; ++d)
                phi[idx++] = u[c] * u[d];
        #pragma unroll
        for (int c = 0; c < 6; ++c) phi[21 + c] = u[c];
        phi[27] = 1.0f;
        phi[28] = 1.0f;
        phi[29] = phi[30] = phi[31] = 0.0f;
        store_row(phiL, r, phi);
    }

    // ---- psi prep: threads 0..127 (waves 0-1), one i-row each ----
    if (tid < IBLK) {
        const int r = tid;
        const int i = it * IBLK + r;
        const float* Rp = traj_rot + ((size_t)lb * N + i) * 9;
        const float* Rt = true_rot + ((size_t)(b * N + i)) * 9;

        float W0[6], W1[6], W2[6];
        #pragma unroll
        for (int c = 0; c < 3; ++c) {
            W0[c] = Rp[3 * c];      W1[c] = Rp[3 * c + 1];      W2[c] = Rp[3 * c + 2];
            W0[c + 3] = -Rt[3 * c]; W1[c + 3] = -Rt[3 * c + 1]; W2[c + 3] = -Rt[3 * c + 2];
        }
        float u[6] = { tp[3 * i], tp[3 * i + 1], tp[3 * i + 2],
                       tt[3 * i], tt[3 * i + 1], tt[3 * i + 2] };

        float k0 = 0.f, k1 = 0.f, k2 = 0.f;
        #pragma unroll
        for (int c = 0; c < 6; ++c) {
            k0 = fmaf(W0[c], u[c], k0);
            k1 = fmaf(W1[c], u[c], k1);
            k2 = fmaf(W2[c], u[c], k2);
        }
        k0 = -k0; k1 = -k1; k2 = -k2;

        float psi[KF];
        #pragma unroll
        for (int c = 0; c < 6; ++c)
            psi[c] = fmaf(W0[c], W0[c], fmaf(W1[c], W1[c], W2[c] * W2[c]));
        int idx = 6;
        #pragma unroll
        for (int c = 0; c < 6; ++c)
            #pragma unroll
            for (int d = c + 1; d < 6; ++d)
                psi[idx++] = 2.0f * fmaf(W0[c], W0[d], fmaf(W1[c], W1[d], W2[c] * W2[d]));
        #pragma unroll
        for (int c = 0; c < 6; ++c)
            psi[21 + c] = 2.0f * fmaf(W0[c], k0, fmaf(W1[c], k1, W2[c] * k2));
        psi[27] = fmaf(k0, k0, fmaf(k1, k1, fmaf(k2, k2, FAPE_EPS)));
        // residual vs the SAME hw conversion the store uses -> self-consistent
        psi[28] = psi[27] - bf2f((unsigned short)(cvt_pk(psi[27], psi[27]) & 0xffffu));
        psi[29] = psi[30] = psi[31] = 0.0f;
        store_row(psiL, r, psi);
    }

    // ---- torsion: wave 3, one item per lane (32 items per block) ----
    if (tid >= 192) {
        const int t = tid - 192;
        float val = 0.0f;
        if (t < TORS_PER_BLK) {
            const int n  = (bid & 63) * TORS_PER_BLK + t;
            const int g  = lb * N + n;
            const int bn = b * N + n;
            const float* p  = traj_tors + (size_t)g * 14;
            const float* tr = t_true + (size_t)bn * 14;
            const float* al = t_alt  + (size_t)bn * 14;

            float st = 0.0f, sa = 0.0f;
            #pragma unroll
            for (int k = 0; k < 7; ++k) {
                const float px = p[2 * k], py = p[2 * k + 1];
                const float nrm = fast_sqrtf(fmaf(px, px, fmaf(py, py, TEPS)));
                const float inv = __builtin_amdgcn_rcpf(nrm);
                const float pnx = px * inv, pny = py * inv;
                const float tx = tr[2 * k] - pnx, ty = tr[2 * k + 1] - pny;
                const float ax = al[2 * k] - pnx, ay = al[2 * k + 1] - pny;
                const float dt = fast_sqrtf(fmaf(tx, tx, fmaf(ty, ty, TEPS)));
                const float da = fast_sqrtf(fmaf(ax, ax, fmaf(ay, ay, TEPS)));
                st += fminf(dt, da);
                sa += fabsf(nrm - 1.0f);
            }
            val = (st + 0.02f * sa) * (1.0f / 7.0f);
        }
        val = wave_reduce_sum(val);
        if (tid == 192) tors_s = val;
    }

    __syncthreads();

    // ---- MFMA pair loop: 4 waves, each 64 i x 256 j ----
    const int w    = tid >> 6;
    const int lane = tid & 63;
    const int wm   = w >> 1;             // i half (64 rows)
    const int wn   = w & 1;              // j half (256 cols)
    const int r15  = lane & 15;
    const int cch  = lane >> 4;          // k-chunk 0..3

    bf16x8 a[4];                         // 4 A-frags in registers (16 VGPR)
    #pragma unroll
    for (int s = 0; s < 4; ++s)
        a[s] = load_frag(psiL, wm * 64 + s * 16 + r15, cch);

    const f32x4 z = { 0.f, 0.f, 0.f, 0.f };
    float acc0 = 0.f, acc1 = 0.f, acc2 = 0.f, acc3 = 0.f;

    #pragma unroll
    for (int jp = 0; jp < 4; ++jp) {             // 4 j-passes of 64
        const int rb = wn * 256 + jp * 64 + r15;
        #pragma unroll
        for (int q = 0; q < 4; ++q) {            // 4 B-frags per pass
            const bf16x8 bq = load_frag(phiL, rb + q * 16, cch);
            f32x4 d[4];
            #pragma unroll
            for (int s = 0; s < 4; ++s)
                d[s] = __builtin_amdgcn_mfma_f32_16x16x32_bf16(a[s], bq, z, 0, 0, 0);
            #pragma unroll
            for (int s = 0; s < 4; ++s) {
                acc0 += fast_sqrtf(__builtin_amdgcn_fmed3f(d[s][0], 0.f, D_CLAMP2));
                acc1 += fast_sqrtf(__builtin_amdgcn_fmed3f(d[s][1], 0.f, D_CLAMP2));
                acc2 += fast_sqrtf(__builtin_amdgcn_fmed3f(d[s][2], 0.f, D_CLAMP2));
                acc3 += fast_sqrtf(__builtin_amdgcn_fmed3f(d[s][3], 0.f, D_CLAMP2));
            }
        }
    }

    const float tot = block_reduce_sum((acc0 + acc1) + (acc2 + acc3));
    if (tid == 0) {
        const float inv_pairs = 1.0f / ((float)N * (float)N * Z_CONST);
        partials[bid] = tot * inv_pairs + tors_s * (1.0f / (float)N);
    }
}

// ---------------------------------------------------------------------------
// Finalize: out[b] = (1/L) * sum over partials of that b (lb = t>>6)
// ---------------------------------------------------------------------------
__global__ __launch_bounds__(THREADS)
void finalize_kernel(const float* __restrict__ partials,
                     float* __restrict__ out)
{
    float fs0 = 0.0f, fs1 = 0.0f;
    for (int t = threadIdx.x; t < FAPE_BLOCKS; t += THREADS) {
        const float v = partials[t];
        if ((t >> 6) & 1) fs1 += v; else fs0 += v;
    }
    const float F0 = block_reduce_sum(fs0);
    const float F1 = block_reduce_sum(fs1);
    if (threadIdx.x == 0) {
        out[0] = F0 / (float)L;
        out[1] = F1 / (float)L;
    }
}

extern "C" void kernel_launch(void* const* d_in, const int* in_sizes, int n_in,
                              void* d_out, int out_size, void* d_ws, size_t ws_size,
                              hipStream_t stream)
{
    const float* traj_rot   = (const float*)d_in[0];
    const float* traj_trans = (const float*)d_in[1];
    const float* traj_tors  = (const float*)d_in[2];
    const float* true_rot   = (const float*)d_in[3];
    const float* true_trans = (const float*)d_in[4];
    const float* true_ta    = (const float*)d_in[5];
    const float* true_taa   = (const float*)d_in[6];

    float* out      = (float*)d_out;
    float* partials = (float*)d_ws;                  // FAPE_BLOCKS floats

    fape_all_kernel<<<FAPE_BLOCKS, THREADS, 0, stream>>>(
        traj_rot, traj_trans, traj_tors, true_rot, true_trans,
        true_ta, true_taa, partials);
    finalize_kernel<<<1, THREADS, 0, stream>>>(partials, out);
}

// Round 12
// 20.605 us; speedup vs baseline: 1.2465x; 1.0080x over previous
//
#include <hip/hip_runtime.h>
#include <math.h>

// Problem constants (setup_inputs: L=8, B=2, N=2048)
constexpr int L = 8;
constexpr int B = 2;
constexpr int N = 2048;
constexpr int LB = L * B;            // 16
constexpr int KF = 32;               // padded feature dim (28 used + residual)

constexpr float D_CLAMP2 = 100.0f;   // clamp on squared distance
constexpr float FAPE_EPS = 1e-4f;
constexpr float Z_CONST  = 10.0f;
constexpr float TEPS     = 1e-8f;

constexpr int THREADS = 256;                 // 4 waves
constexpr int IBLK    = 128;                 // i rows per block
constexpr int JCH     = 512;                 // j cols per block
constexpr int NIT     = N / IBLK;            // 16 i-tiles per (l,b)
constexpr int JSPLIT  = N / JCH;             // 4 j-chunks per (l,b)
constexpr int BLK_PER_LB  = NIT * JSPLIT;    // 64
constexpr int FAPE_BLOCKS = LB * BLK_PER_LB; // 1024 -> 4 blocks/CU (40KB LDS)
constexpr int TORS_PER_BLK = N / BLK_PER_LB; // 32 torsion items per block
constexpr int NXCD = 8;
constexpr int BLK_PER_XCD = FAPE_BLOCKS / NXCD;  // 128 (= 2 lb per XCD)

typedef __attribute__((ext_vector_type(8))) short bf16x8;
typedef __attribute__((ext_vector_type(4))) float f32x4;

__device__ __forceinline__ float fast_sqrtf(float x) {
    return __builtin_amdgcn_sqrtf(x);
}
// HW packed f32->bf16 (RNE on gfx950); 1 instr per 2 values
__device__ __forceinline__ unsigned cvt_pk(float lo, float hi) {
    unsigned r;
    asm("v_cvt_pk_bf16_f32 %0, %1, %2" : "=v"(r) : "v"(lo), "v"(hi));
    return r;
}
__device__ __forceinline__ float bf2f(unsigned short h) {
    return __uint_as_float((unsigned)h << 16);
}

__device__ __forceinline__ float wave_reduce_sum(float v) {
    #pragma unroll
    for (int off = 32; off > 0; off >>= 1)
        v += __shfl_down(v, off, 64);
    return v;            // valid in lane 0
}

__device__ __forceinline__ float block_reduce_sum(float v) {
    __shared__ float s[4];
    v = wave_reduce_sum(v);
    int lane = threadIdx.x & 63;
    int w    = threadIdx.x >> 6;
    __syncthreads();
    if (lane == 0) s[w] = v;
    __syncthreads();
    return s[0] + s[1] + s[2] + s[3];   // fixed order -> deterministic
}

// LDS chunk swizzle: 16B chunk c of row r stored at position c ^ ((r>>1)&3).
// Write (64 lanes x 4 chunks) and MFMA-fragment read (16 rows x 4 k-chunks)
// both hit each bank exactly twice per wave access = structural minimum
// (verified 0 SQ_LDS_BANK_CONFLICT in rounds 7-11).
__device__ __forceinline__ void store_row(short* base, int r, const float* f) {
    #pragma unroll
    for (int c = 0; c < 4; ++c) {
        union { unsigned u[4]; bf16x8 v; } q;
        #pragma unroll
        for (int e = 0; e < 4; ++e)
            q.u[e] = cvt_pk(f[8 * c + 2 * e], f[8 * c + 2 * e + 1]);
        const int p = c ^ ((r >> 1) & 3);
        *(bf16x8*)(base + r * KF + p * 8) = q.v;
    }
}
__device__ __forceinline__ bf16x8 load_frag(const short* base, int r, int c) {
    const int p = c ^ ((r >> 1) & 3);
    return *(const bf16x8*)(base + r * KF + p * 8);
}

// ---------------------------------------------------------------------------
// Self-sufficient FAPE block (round-8/11 structure + XCD-aware swizzle):
// 128 i x 512 j, 4 waves, 40KB LDS -> 4 blocks/CU.
// Hardware blockIdx round-robins XCDs (bid%8); remap so XCD k owns logical
// blocks [128k,128k+128) = lb {2k,2k+1} -> per-XCD L2 sees ~1/8 of inputs
// and the 16x phi-row reuse is L2-local. 1024 % 8 == 0 -> bijective.
// Factorization: ||W u_j + k||^2 + eps = psi(i) . phi(j), W=[Rp^T|-Rt^T],
// k = -W u_i.  psi: [0..5]=Q_cc, [6..20]=2Q_cd, [21..26]=2(W^T k)_c,
// [27]=|k|^2+eps, [28]=bf16 residual of [27]; phi: [u_c^2, u_c u_d, u_c, 1, 1].
// Partials stored b-major: pidx = b*512 + l*64 + (block index within lb).
// ---------------------------------------------------------------------------
__global__ __launch_bounds__(THREADS)
void fape_all_kernel(const float* __restrict__ traj_rot,    // [L,B,N,3,3]
                     const float* __restrict__ traj_trans,  // [L,B,N,3]
                     const float* __restrict__ traj_tors,   // [L,B,N,7,2]
                     const float* __restrict__ true_rot,    // [B,N,3,3]
                     const float* __restrict__ true_trans,  // [B,N,3]
                     const float* __restrict__ t_true,      // [B,N,7,2]
                     const float* __restrict__ t_alt,       // [B,N,7,2]
                     float* __restrict__ partials)          // [B][512]
{
    __shared__ short phiL[JCH * KF];    // 32 KB
    __shared__ short psiL[IBLK * KF];   // 8 KB
    __shared__ float tors_s;

    // XCD-aware remap (hardware: bid%8 = XCD)
    const int hbid = blockIdx.x;
    const int bid  = (hbid & (NXCD - 1)) * BLK_PER_XCD + (hbid >> 3);

    const int jh  = bid & (JSPLIT - 1);
    const int it  = (bid >> 2) & (NIT - 1);
    const int lb  = bid >> 6;            // 64 blocks per lb
    const int b   = lb & (B - 1);
    const int tid = threadIdx.x;

    const float* tp = traj_trans + (size_t)lb * N * 3;
    const float* tt = true_trans + (size_t)b  * N * 3;

    // ---- phi prep: rows tid and tid+256 ----
    #pragma unroll
    for (int half = 0; half < 2; ++half) {
        const int r = tid + half * THREADS;      // 0..511
        const int j = jh * JCH + r;
        float u[6] = { tp[3 * j], tp[3 * j + 1], tp[3 * j + 2],
                       tt[3 * j], tt[3 * j + 1], tt[3 * j + 2] };
        float phi[KF];
        #pragma unroll
        for (int c = 0; c < 6; ++c) phi[c] = u[c] * u[c];
        int idx = 6;
        #pragma unroll
        for (int c = 0; c < 6; ++c)
            #pragma unroll
            for (int d = c + 1; d < 6; ++d)
                phi[idx++] = u[c] * u[d];
        #pragma unroll
        for (int c = 0; c < 6; ++c) phi[21 + c] = u[c];
        phi[27] = 1.0f;
        phi[28] = 1.0f;
        phi[29] = phi[30] = phi[31] = 0.0f;
        store_row(phiL, r, phi);
    }

    // ---- psi prep: threads 0..127 (waves 0-1), one i-row each ----
    if (tid < IBLK) {
        const int r = tid;
        const int i = it * IBLK + r;
        const float* Rp = traj_rot + ((size_t)lb * N + i) * 9;
        const float* Rt = true_rot + ((size_t)(b * N + i)) * 9;

        float W0[6], W1[6], W2[6];
        #pragma unroll
        for (int c = 0; c < 3; ++c) {
            W0[c] = Rp[3 * c];      W1[c] = Rp[3 * c + 1];      W2[c] = Rp[3 * c + 2];
            W0[c + 3] = -Rt[3 * c]; W1[c + 3] = -Rt[3 * c + 1]; W2[c + 3] = -Rt[3 * c + 2];
        }
        float u[6] = { tp[3 * i], tp[3 * i + 1], tp[3 * i + 2],
                       tt[3 * i], tt[3 * i + 1], tt[3 * i + 2] };

        float k0 = 0.f, k1 = 0.f, k2 = 0.f;
        #pragma unroll
        for (int c = 0; c < 6; ++c) {
            k0 = fmaf(W0[c], u[c], k0);
            k1 = fmaf(W1[c], u[c], k1);
            k2 = fmaf(W2[c], u[c], k2);
        }
        k0 = -k0; k1 = -k1; k2 = -k2;

        float psi[KF];
        #pragma unroll
        for (int c = 0; c < 6; ++c)
            psi[c] = fmaf(W0[c], W0[c], fmaf(W1[c], W1[c], W2[c] * W2[c]));
        int idx = 6;
        #pragma unroll
        for (int c = 0; c < 6; ++c)
            #pragma unroll
            for (int d = c + 1; d < 6; ++d)
                psi[idx++] = 2.0f * fmaf(W0[c], W0[d], fmaf(W1[c], W1[d], W2[c] * W2[d]));
        #pragma unroll
        for (int c = 0; c < 6; ++c)
            psi[21 + c] = 2.0f * fmaf(W0[c], k0, fmaf(W1[c], k1, W2[c] * k2));
        psi[27] = fmaf(k0, k0, fmaf(k1, k1, fmaf(k2, k2, FAPE_EPS)));
        // residual vs the SAME hw conversion the store uses -> self-consistent
        psi[28] = psi[27] - bf2f((unsigned short)(cvt_pk(psi[27], psi[27]) & 0xffffu));
        psi[29] = psi[30] = psi[31] = 0.0f;
        store_row(psiL, r, psi);
    }

    // ---- torsion: wave 3, one item per lane (32 items per block) ----
    if (tid >= 192) {
        const int t = tid - 192;
        float val = 0.0f;
        if (t < TORS_PER_BLK) {
            const int n  = (bid & 63) * TORS_PER_BLK + t;
            const int g  = lb * N + n;
            const int bn = b * N + n;
            const float* p  = traj_tors + (size_t)g * 14;
            const float* tr = t_true + (size_t)bn * 14;
            const float* al = t_alt  + (size_t)bn * 14;

            float st = 0.0f, sa = 0.0f;
            #pragma unroll
            for (int k = 0; k < 7; ++k) {
                const float px = p[2 * k], py = p[2 * k + 1];
                const float nrm = fast_sqrtf(fmaf(px, px, fmaf(py, py, TEPS)));
                const float inv = __builtin_amdgcn_rcpf(nrm);
                const float pnx = px * inv, pny = py * inv;
                const float tx = tr[2 * k] - pnx, ty = tr[2 * k + 1] - pny;
                const float ax = al[2 * k] - pnx, ay = al[2 * k + 1] - pny;
                const float dt = fast_sqrtf(fmaf(tx, tx, fmaf(ty, ty, TEPS)));
                const float da = fast_sqrtf(fmaf(ax, ax, fmaf(ay, ay, TEPS)));
                st += fminf(dt, da);
                sa += fabsf(nrm - 1.0f);
            }
            val = (st + 0.02f * sa) * (1.0f / 7.0f);
        }
        val = wave_reduce_sum(val);
        if (tid == 192) tors_s = val;
    }

    __syncthreads();

    // ---- MFMA pair loop: 4 waves, each 64 i x 256 j ----
    const int w    = tid >> 6;
    const int lane = tid & 63;
    const int wm   = w >> 1;             // i half (64 rows)
    const int wn   = w & 1;              // j half (256 cols)
    const int r15  = lane & 15;
    const int cch  = lane >> 4;          // k-chunk 0..3

    bf16x8 a[4];                         // 4 A-frags in registers (16 VGPR)
    #pragma unroll
    for (int s = 0; s < 4; ++s)
        a[s] = load_frag(psiL, wm * 64 + s * 16 + r15, cch);

    const f32x4 z = { 0.f, 0.f, 0.f, 0.f };
    float acc0 = 0.f, acc1 = 0.f, acc2 = 0.f, acc3 = 0.f;

    #pragma unroll
    for (int jp = 0; jp < 4; ++jp) {             // 4 j-passes of 64
        const int rb = wn * 256 + jp * 64 + r15;
        #pragma unroll
        for (int q = 0; q < 4; ++q) {            // 4 B-frags per pass
            const bf16x8 bq = load_frag(phiL, rb + q * 16, cch);
            f32x4 d[4];
            #pragma unroll
            for (int s = 0; s < 4; ++s)
                d[s] = __builtin_amdgcn_mfma_f32_16x16x32_bf16(a[s], bq, z, 0, 0, 0);
            #pragma unroll
            for (int s = 0; s < 4; ++s) {
                acc0 += fast_sqrtf(__builtin_amdgcn_fmed3f(d[s][0], 0.f, D_CLAMP2));
                acc1 += fast_sqrtf(__builtin_amdgcn_fmed3f(d[s][1], 0.f, D_CLAMP2));
                acc2 += fast_sqrtf(__builtin_amdgcn_fmed3f(d[s][2], 0.f, D_CLAMP2));
                acc3 += fast_sqrtf(__builtin_amdgcn_fmed3f(d[s][3], 0.f, D_CLAMP2));
            }
        }
    }

    const float tot = block_reduce_sum((acc0 + acc1) + (acc2 + acc3));
    if (tid == 0) {
        const float inv_pairs = 1.0f / ((float)N * (float)N * Z_CONST);
        // b-major partials: [b][l*64 + (it*4+jh)]
        const int pidx = b * (FAPE_BLOCKS / B) + (lb >> 1) * BLK_PER_LB + (bid & 63);
        partials[pidx] = tot * inv_pairs + tors_s * (1.0f / (float)N);
    }
}

// ---------------------------------------------------------------------------
// Finalize: 2 blocks, block b sums its contiguous 512 partials, /L.
// ---------------------------------------------------------------------------
__global__ __launch_bounds__(THREADS)
void finalize_kernel(const float* __restrict__ partials,
                     float* __restrict__ out)
{
    const int b = blockIdx.x;
    const float* p = partials + (size_t)b * (FAPE_BLOCKS / B);
    float fs = 0.0f;
    for (int t = threadIdx.x; t < FAPE_BLOCKS / B; t += THREADS)
        fs += p[t];
    const float F = block_reduce_sum(fs);
    if (threadIdx.x == 0)
        out[b] = F / (float)L;
}

extern "C" void kernel_launch(void* const* d_in, const int* in_sizes, int n_in,
                              void* d_out, int out_size, void* d_ws, size_t ws_size,
                              hipStream_t stream)
{
    const float* traj_rot   = (const float*)d_in[0];
    const float* traj_trans = (const float*)d_in[1];
    const float* traj_tors  = (const float*)d_in[2];
    const float* true_rot   = (const float*)d_in[3];
    const float* true_trans = (const float*)d_in[4];
    const float* true_ta    = (const float*)d_in[5];
    const float* true_taa   = (const float*)d_in[6];

    float* out      = (float*)d_out;
    float* partials = (float*)d_ws;                  // [B][512]

    fape_all_kernel<<<FAPE_BLOCKS, THREADS, 0, stream>>>(
        traj_rot, traj_trans, traj_tors, true_rot, true_trans,
        true_ta, true_taa, partials);
    finalize_kernel<<<B, THREADS, 0, stream>>>(partials, out);
}